// Round 7
// baseline (100.372 us; speedup 1.0000x reference)
//
#include <hip/hip_runtime.h>

#define NPTS  4096
#define KNN   16
#define K1    17            // KNN + self
#define WPB   4             // waves (queries) per main block
#define BLK   (WPB * 64)    // 256
#define BPB   (NPTS / WPB)  // 1024 main blocks per batch
#define NBLK  64            // candidate blocks per batch (NPTS/64) == wave width
#define CELLS 4096          // 16^3 Morton cells
#define EPSF  1e-10f

__device__ __forceinline__ unsigned umin_(unsigned a, unsigned b) { return a < b ? a : b; }
__device__ __forceinline__ unsigned umax_(unsigned a, unsigned b) { return a < b ? b : a; }

// spread 4 bits to positions 0,3,6,9
__device__ __forceinline__ unsigned sp4(int v) {
    unsigned x = (unsigned)v;
    return (x & 1u) | ((x & 2u) << 2) | ((x & 4u) << 4) | ((x & 8u) << 6);
}

// ---- Kernel 1: per-batch counting sort by 12-bit Morton cell (16^3 over
// [-4,4)^3, 0.5-unit cells) + per-64-block bboxes. Sort is permutation-only
// (exactness never depends on it); bboxes are true min/max of actual points.
__global__ __launch_bounds__(1024) void sort_kernel(
    const float* __restrict__ pref,
    float2* __restrict__ wxy, float* __restrict__ wz, int* __restrict__ widx,
    float* __restrict__ wbb)
{
    __shared__ unsigned hist[CELLS];          // 16 KB
    __shared__ unsigned short cells[NPTS];    // 8 KB
    __shared__ unsigned wofs[16];
    const int tid  = threadIdx.x;
    const int lane = tid & 63, w = tid >> 6;
    const int b = blockIdx.x;
    const float* prb = pref + (size_t)b * NPTS * 3;
    const size_t base = (size_t)b * NPTS;

    for (int t = tid; t < CELLS; t += 1024) hist[t] = 0u;
    __syncthreads();

    for (int p = tid; p < NPTS; p += 1024) {
        float x = prb[3 * p + 0], y = prb[3 * p + 1], z = prb[3 * p + 2];
        int cx = min(15, max(0, (int)((x + 4.0f) * 2.0f)));
        int cy = min(15, max(0, (int)((y + 4.0f) * 2.0f)));
        int cz = min(15, max(0, (int)((z + 4.0f) * 2.0f)));
        unsigned m = sp4(cx) | (sp4(cy) << 1) | (sp4(cz) << 2);
        cells[p] = (unsigned short)m;
        atomicAdd(&hist[m], 1u);
    }
    __syncthreads();

    // Exclusive scan of hist[4096]; thread t owns cells 4t..4t+3.
    unsigned l0 = hist[4 * tid + 0], l1 = hist[4 * tid + 1];
    unsigned l2 = hist[4 * tid + 2], l3 = hist[4 * tid + 3];
    unsigned s = l0 + l1 + l2 + l3;
    unsigned run = s;
#pragma unroll
    for (int d = 1; d < 64; d <<= 1) {
        unsigned o = __shfl_up(run, d);
        if (lane >= d) run += o;
    }
    if (lane == 63) wofs[w] = run;
    __syncthreads();
    if (tid == 0) {
        unsigned acc = 0;
#pragma unroll
        for (int k = 0; k < 16; ++k) { unsigned t2 = wofs[k]; wofs[k] = acc; acc += t2; }
    }
    __syncthreads();
    unsigned excl = wofs[w] + run - s;
    hist[4 * tid + 0] = excl;
    hist[4 * tid + 1] = excl + l0;
    hist[4 * tid + 2] = excl + l0 + l1;
    hist[4 * tid + 3] = excl + l0 + l1 + l2;
    __syncthreads();

    for (int p = tid; p < NPTS; p += 1024) {
        unsigned c = cells[p];
        unsigned pos = atomicAdd(&hist[c], 1u);
        wxy[base + pos]  = make_float2(prb[3 * p + 0], prb[3 * p + 1]);
        wz[base + pos]   = prb[3 * p + 2];
        widx[base + pos] = p;
    }
    __syncthreads();

    // Per-block bboxes: wave w handles blocks w, w+16, w+32, w+48.
#pragma unroll
    for (int rep = 0; rep < 4; ++rep) {
        int blk = w + rep * 16;
        int j = blk * 64 + lane;
        float2 c = wxy[base + j];
        float z  = wz[base + j];
        float mnx = c.x, mxx = c.x, mny = c.y, mxy2 = c.y, mnz = z, mxz = z;
#pragma unroll
        for (int d = 32; d > 0; d >>= 1) {
            mnx  = fminf(mnx,  __shfl_xor(mnx,  d));
            mxx  = fmaxf(mxx,  __shfl_xor(mxx,  d));
            mny  = fminf(mny,  __shfl_xor(mny,  d));
            mxy2 = fmaxf(mxy2, __shfl_xor(mxy2, d));
            mnz  = fminf(mnz,  __shfl_xor(mnz,  d));
            mxz  = fmaxf(mxz,  __shfl_xor(mxz,  d));
        }
        if (lane == 0) {
            float* o = wbb + ((size_t)b * NBLK + blk) * 6;
            o[0] = mnx; o[1] = mny; o[2] = mnz; o[3] = mxx; o[4] = mxy2; o[5] = mxz;
        }
    }
}

// ---- Kernel 2: one wave per query; bbox-pruned exact top-17.
#define EVENTS(KEY) do {                                                      \
    unsigned long long m_ = __ballot((KEY) < thr);                            \
    if (m_) {                                                                 \
        do {                                                                  \
            int l_ = __ffsll(m_) - 1;                                         \
            m_ &= m_ - 1;                                                     \
            unsigned kk_ = (unsigned)__builtin_amdgcn_readlane((int)(KEY), l_);\
            unsigned long long lt_ = __ballot(arr < kk_) & 0x1FFFFull;        \
            int pos_ = __popcll(lt_);                                         \
            unsigned up_ = __shfl_up(arr, 1);                                 \
            arr = (lane == pos_) ? kk_ : ((lane > pos_) ? up_ : arr);         \
        } while (m_);                                                         \
        thr = (unsigned)__builtin_amdgcn_readlane((int)arr, K1 - 1);          \
    } } while (0)

__global__ __launch_bounds__(BLK, 8) void knn_main_kernel(
    const float* __restrict__ ppred,
    const float2* __restrict__ wxy, const float* __restrict__ wz,
    const int* __restrict__ widx, const float* __restrict__ wbb,
    float* __restrict__ partials)
{
    __shared__ float wsum[WPB];
    const int w    = threadIdx.x >> 6;
    const int lane = threadIdx.x & 63;
    const int q    = blockIdx.x * WPB + w;
    const int b    = q >> 12;
    const int p    = q & (NPTS - 1);      // sorted position = query
    const size_t base = (size_t)b * NPTS;

    const float2 qv = wxy[base + p];
    const float qx = qv.x, qy = qv.y, qz = wz[base + p];
    const int p0 = p & ~63, ownblk = p >> 6;

    // Bootstrap: bitonic sort of own 64-block (contains self at d2 = +0.0).
    unsigned arr;
    {
        int j = p0 + lane;
        float2 c = wxy[base + j];
        float dz0 = wz[base + j] - qz;
        float dx = c.x - qx, dy = c.y - qy;
        float d2 = dx * dx + dy * dy + dz0 * dz0;
        arr = (__float_as_uint(d2) & 0xFFFFF000u) | (unsigned)j;
    }
#pragma unroll
    for (int k = 2; k <= 64; k <<= 1) {
#pragma unroll
        for (int j = k >> 1; j > 0; j >>= 1) {
            unsigned other = __shfl_xor(arr, j);
            bool takeMin = (((lane & j) == 0) == ((lane & k) == 0));
            unsigned mn = umin_(arr, other), mx = umax_(arr, other);
            arr = takeMin ? mn : mx;
        }
    }
    unsigned thr = (unsigned)__builtin_amdgcn_readlane((int)arr, K1 - 1);

    // Lane l = candidate block l: conservative lower-bound key from bbox.
    const float* bbp = wbb + ((size_t)b * NBLK + lane) * 6;
    float ddx = fmaxf(fmaxf(bbp[0] - qx, qx - bbp[3]), 0.0f);
    float ddy = fmaxf(fmaxf(bbp[1] - qy, qy - bbp[4]), 0.0f);
    float ddz = fmaxf(fmaxf(bbp[2] - qz, qz - bbp[5]), 0.0f);
    float bd2 = ddx * ddx + ddy * ddy + ddz * ddz;
    unsigned bkey = __float_as_uint(bd2) & 0xFFFFF000u;
    // Pruning is exact: truncation preserves order, real keys >= bkey,
    // thr only decreases -> any block failing (bkey < thr) can never
    // contribute to the final top-17.
    unsigned long long mask = __ballot(bkey < thr) & ~(1ull << ownblk);

    while (mask) {
        int jb = __ffsll(mask) - 1;
        mask &= mask - 1;
        if ((unsigned)__builtin_amdgcn_readlane((int)bkey, jb) < thr) {  // re-check tightened thr
            int j = jb * 64 + lane;
            float2 a = wxy[base + j];
            float z  = wz[base + j];
            float dx = a.x - qx, dy = a.y - qy, dz2 = z - qz;
            float d2 = dx * dx + dy * dy + dz2 * dz2;
            unsigned key = (__float_as_uint(d2) & 0xFFFFF000u) | (unsigned)j;
            EVENTS(key);
        }
    }

    // Epilogue: lanes 1..16 hold the 16 nearest neighbors (lane 0 = self).
    const float* ppb = ppred + (size_t)b * NPTS * 3;
    const int iorig = widx[base + p];   // uniform -> broadcast
    float s = 0.f;
    if (lane >= 1 && lane <= KNN) {
        int js = (int)(arr & 0xFFFu);
        float2 rc = wxy[base + js];
        float rx = rc.x - qx, ry = rc.y - qy, rz = wz[base + js] - qz;
        float dref = sqrtf(rx * rx + ry * ry + rz * rz);
        int nj = widx[base + js];
        float px = ppb[3 * iorig + 0], py = ppb[3 * iorig + 1], pz = ppb[3 * iorig + 2];
        float ax = ppb[3 * nj + 0] - px;
        float ay = ppb[3 * nj + 1] - py;
        float az = ppb[3 * nj + 2] - pz;
        float dpred = sqrtf(ax * ax + ay * ay + az * az);
        s = fmaxf(dpred / (dref + EPSF) - 1.0f, 0.0f);
    }
    for (int off = 32; off > 0; off >>= 1) s += __shfl_down(s, off);
    if (lane == 0) wsum[w] = s;
    __syncthreads();
    if (threadIdx.x == 0) {
        float t = 0.f;
#pragma unroll
        for (int k = 0; k < WPB; ++k) t += wsum[k];
        partials[blockIdx.x] = t;
    }
}

// ---- Kernel 3: deterministic single-block final reduction.
__global__ __launch_bounds__(1024) void reduce_kernel(
    const float* __restrict__ partials, int n, float* __restrict__ out, float scale)
{
    __shared__ float wsum[16];
    float s = 0.f;
    for (int idx = threadIdx.x; idx < n; idx += 1024) s += partials[idx];
    for (int off = 32; off > 0; off >>= 1) s += __shfl_down(s, off);
    if ((threadIdx.x & 63) == 0) wsum[threadIdx.x >> 6] = s;
    __syncthreads();
    if (threadIdx.x == 0) {
        float t = 0.f;
#pragma unroll
        for (int k = 0; k < 16; ++k) t += wsum[k];
        out[0] = t * scale;
    }
}

extern "C" void kernel_launch(void* const* d_in, const int* in_sizes, int n_in,
                              void* d_out, int out_size, void* d_ws, size_t ws_size,
                              hipStream_t stream) {
    const float* pref  = (const float*)d_in[0];
    const float* ppred = (const float*)d_in[1];
    float* out = (float*)d_out;

    const int B = in_sizes[0] / (NPTS * 3);
    const int nblocks = B * BPB;
    const float scale = 1.0f / ((float)B * (float)NPTS * (float)KNN);

    char* ws = (char*)d_ws;
    float2* wxy  = (float2*)ws;                                   // B*N*8 bytes
    float*  wz   = (float*)(ws + (size_t)B * NPTS * 8);           // B*N*4
    int*    widx = (int*)  (ws + (size_t)B * NPTS * 12);          // B*N*4
    float*  wbb  = (float*)(ws + (size_t)B * NPTS * 16);          // B*64*6*4
    float*  partials = (float*)(ws + (size_t)B * NPTS * 16 + (size_t)B * NBLK * 6 * 4);

    sort_kernel<<<dim3(B), dim3(1024), 0, stream>>>(pref, wxy, wz, widx, wbb);
    knn_main_kernel<<<dim3(nblocks), dim3(BLK), 0, stream>>>(ppred, wxy, wz, widx, wbb, partials);
    reduce_kernel<<<dim3(1), dim3(1024), 0, stream>>>(partials, nblocks, out, scale);
}